// Round 6
// baseline (414.265 us; speedup 1.0000x reference)
//
#include <hip/hip_runtime.h>

// ---- problem constants ----
#define HWN 4096
#define CCH 512
#define NHEAD 8
#define DHD 64
#define NBATCH 2
#define QK_SCALE 0.35355339059327373f   // 64^-0.25
#define LOG2E    1.4426950408889634f

using floatx4 = __attribute__((ext_vector_type(4))) float;
using bf16x8  = __attribute__((ext_vector_type(8))) short;
using bf16x4  = __attribute__((ext_vector_type(4))) short;

__device__ __forceinline__ unsigned short f2b(float f) {
  union { float f; unsigned u; } x; x.f = f;
  unsigned r = x.u + 0x7FFFu + ((x.u >> 16) & 1u);
  return (unsigned short)(r >> 16);
}

__device__ __forceinline__ float fast_exp2(float x) {
#if __has_builtin(__builtin_amdgcn_exp2f)
  return __builtin_amdgcn_exp2f(x);
#else
  return __expf(x * 0.69314718056f);
#endif
}

// pack bf16(lo),bf16(hi) from two floats in ONE v_perm_b32 (truncating round)
__device__ __forceinline__ unsigned pack_bf16_trunc(float lo, float hi) {
  return __builtin_amdgcn_perm(__float_as_uint(hi), __float_as_uint(lo), 0x07060302u);
}

// ---------------- 1. GroupNorm partial sums: grid (64 groups, 8 parts) ----------------
// stat[bg] += sum, stat[64+bg] += sumsq  (stat zeroed by hipMemsetAsync)
__global__ __launch_bounds__(256) void gn_stats(const float* __restrict__ x,
                                                float* __restrict__ stat) {
  int bg = blockIdx.x;
  const float4* p = (const float4*)(x + (size_t)bg * 65536) + blockIdx.y * 2048;
  float s = 0.f, ss = 0.f;
  for (int i = threadIdx.x; i < 2048; i += 256) {
    float4 v = p[i];
    s  += v.x + v.y + v.z + v.w;
    ss += v.x*v.x + v.y*v.y + v.z*v.z + v.w*v.w;
  }
  for (int off = 32; off; off >>= 1) {
    s  += __shfl_xor(s, off);
    ss += __shfl_xor(ss, off);
  }
  __shared__ float red[8];
  int w = threadIdx.x >> 6;
  if ((threadIdx.x & 63) == 0) { red[w] = s; red[4 + w] = ss; }
  __syncthreads();
  if (threadIdx.x == 0) {
    float S  = red[0] + red[1] + red[2] + red[3];
    float SS = red[4] + red[5] + red[6] + red[7];
    atomicAdd(&stat[bg], S);
    atomicAdd(&stat[64 + bg], SS);
  }
}

// ---------------- 2. weight prep: fp32 -> bf16, fold SCALE (and log2e into q) ----------------
__global__ __launch_bounds__(256) void prep_w(
    const float* __restrict__ wq, const float* __restrict__ wk,
    const float* __restrict__ wv, const float* __restrict__ wp,
    const float* __restrict__ bq, const float* __restrict__ bk,
    const float* __restrict__ bv,
    unsigned short* __restrict__ Wqkv, unsigned short* __restrict__ Wp,
    float* __restrict__ bqkv) {
  int i = blockIdx.x * 256 + threadIdx.x;
  if (i < 786432) {                       // Wqkv: rows 0-511 q, 512-1023 k, 1024-1535 v
    int row = i >> 9;
    float v;
    if (row < 512)       v = wq[i] * (QK_SCALE * LOG2E);
    else if (row < 1024) v = wk[i - 262144] * QK_SCALE;
    else                 v = wv[i - 524288];
    Wqkv[i] = f2b(v);
  } else if (i < 1048576) {
    Wp[i - 786432] = f2b(wp[i - 786432]);
  } else if (i < 1050112) {
    int j = i - 1048576;
    float v = (j < 512) ? bq[j] * (QK_SCALE * LOG2E)
            : (j < 1024) ? bk[j - 512] * QK_SCALE
            : bv[j - 1024];
    bqkv[j] = v;
  }
}

// ---------------- 3. normalize + transpose to t[(b*4096+p)*512 + c] bf16 ----------------
// stat holds raw (sum, sumsq); derive mean/rstd here.
__global__ __launch_bounds__(256) void gn_apply(
    const float* __restrict__ x, const float* __restrict__ stat,
    const float* __restrict__ gnw, const float* __restrict__ gnb,
    unsigned short* __restrict__ t) {
  int pt = blockIdx.x & 63;
  int ct = (blockIdx.x >> 6) & 7;
  int b  = blockIdx.x >> 9;
  int c0 = ct * 64, p0 = pt * 64;
  __shared__ float tile[64][68];          // pad 68: bank shift 4/row, float4-aligned
  int tid = threadIdx.x;
  for (int pp = 0; pp < 4; ++pp) {
    int f = (pp * 256 + tid) * 4;
    int cl = f >> 6, pl = f & 63;
    int c = c0 + cl;
    float4 v = *(const float4*)(x + ((size_t)(b * 512 + c)) * 4096 + p0 + pl);
    int g = c >> 4;
    float S    = stat[b * 32 + g];
    float SS   = stat[64 + b * 32 + g];
    float mean = S * (1.f / 65536.f);
    float var  = SS * (1.f / 65536.f) - mean * mean;
    float rstd = rsqrtf(var + 1e-5f);
    float w  = gnw[c] * rstd;
    float bb = gnb[c] - mean * w;
    tile[cl][pl + 0] = v.x * w + bb;
    tile[cl][pl + 1] = v.y * w + bb;
    tile[cl][pl + 2] = v.z * w + bb;
    tile[cl][pl + 3] = v.w * w + bb;
  }
  __syncthreads();
  for (int pp = 0; pp < 2; ++pp) {
    int f = (pp * 256 + tid) * 8;
    int pl = f >> 6, cl = f & 63;
    unsigned short u[8];
#pragma unroll
    for (int j = 0; j < 8; ++j) u[j] = f2b(tile[cl + j][pl]);
    *(uint4*)(t + ((size_t)(b * 4096 + p0 + pl)) * 512 + c0 + cl) = *(uint4*)u;
  }
}

// ---------------- 4. QKV GEMM ----------------
// q/k: [(bh*4096+p)*64+d] bf16 ; v: TRANSPOSED [bh][d][4096] bf16
__global__ __launch_bounds__(256) void gemm_qkv(
    const unsigned short* __restrict__ t, const unsigned short* __restrict__ Wqkv,
    const float* __restrict__ bqkv,
    unsigned short* __restrict__ qo, unsigned short* __restrict__ ko,
    unsigned short* __restrict__ vo) {
  int M0 = blockIdx.x * 64;   // pixel 0..8128
  int N0 = blockIdx.y * 64;   // outch 0..1472
  __shared__ unsigned short At[64][72];
  __shared__ unsigned short Bt[64][72];
  int tid = threadIdx.x, w = tid >> 6, l = tid & 63;
  int quad = l >> 4, m16 = l & 15;
  floatx4 acc[4] = {};
  for (int k0 = 0; k0 < 512; k0 += 64) {
    __syncthreads();
#pragma unroll
    for (int pp = 0; pp < 2; ++pp) {
      int f = (pp * 256 + tid) * 8;
      int r = f >> 6, c = f & 63;
      *(uint4*)&At[r][c] = *(const uint4*)(t    + (size_t)(M0 + r) * 512 + k0 + c);
      *(uint4*)&Bt[r][c] = *(const uint4*)(Wqkv + (size_t)(N0 + r) * 512 + k0 + c);
    }
    __syncthreads();
    bf16x8 af0 = *(const bf16x8*)&At[w * 16 + m16][quad * 8];
    bf16x8 af1 = *(const bf16x8*)&At[w * 16 + m16][32 + quad * 8];
#pragma unroll
    for (int nt = 0; nt < 4; ++nt) {
      bf16x8 b0 = *(const bf16x8*)&Bt[nt * 16 + m16][quad * 8];
      bf16x8 b1 = *(const bf16x8*)&Bt[nt * 16 + m16][32 + quad * 8];
      acc[nt] = __builtin_amdgcn_mfma_f32_16x16x32_bf16(af0, b0, acc[nt], 0, 0, 0);
      acc[nt] = __builtin_amdgcn_mfma_f32_16x16x32_bf16(af1, b1, acc[nt], 0, 0, 0);
    }
  }
  int which = N0 >> 9;
  int head  = (N0 & 511) >> 6;
  if (which == 2) {
    // V: transpose 64x64 tile through LDS, store [bh][d][4096] coalesced
    __syncthreads();
#pragma unroll
    for (int nt = 0; nt < 4; ++nt) {
      int d = nt * 16 + m16;
      float bias = bqkv[N0 + d];
#pragma unroll
      for (int r = 0; r < 4; ++r)
        At[d][w * 16 + quad * 4 + r] = f2b(acc[nt][r] + bias);
    }
    __syncthreads();
    int bb = M0 >> 12, p0 = M0 & 4095;
    unsigned short* dst = vo + ((size_t)(bb * 8 + head) * 64) * 4096;
#pragma unroll
    for (int pp = 0; pp < 2; ++pp) {
      int f = (pp * 256 + tid) * 8;
      int d = f >> 6, pl = f & 63;
      *(uint4*)(dst + (size_t)d * 4096 + p0 + pl) = *(uint4*)&At[d][pl];
    }
  } else {
    unsigned short* dst = (which == 0) ? qo : ko;
#pragma unroll
    for (int nt = 0; nt < 4; ++nt) {
      int n = N0 + nt * 16 + m16;
      float bias = bqkv[n];
      int d = n & 63;
#pragma unroll
      for (int r = 0; r < 4; ++r) {
        int m = M0 + w * 16 + quad * 4 + r;   // pixel 0..8191
        int b = m >> 12, p = m & 4095;
        dst[(((size_t)(b * 8 + head) * 4096 + p) << 6) + d] = f2b(acc[nt][r] + bias);
      }
    }
  }
}

// ---------------- 5. flash attention, KEY-SLICE wave decomposition ----------------
// Each wave owns a 16-key slice of the kt tile and ALL 64 queries (Q frags in
// registers). LDS reads per wave*kt: 2 b128 (K slice) + 4 b64 (V slice) vs 24
// in the query-slice design (4x dedup - waves no longer read identical frags).
// Per-wave private (m,l,accO); one end-of-kernel LSE merge via LDS atomics.
__global__ __launch_bounds__(256, 3) void attn(
    const unsigned short* __restrict__ q, const unsigned short* __restrict__ k,
    const unsigned short* __restrict__ vt, unsigned short* __restrict__ o) {
  int qt = blockIdx.x;           // 0..63
  int bh = blockIdx.y;           // 0..15
  int b = bh >> 3, h = bh & 7;
  __shared__ unsigned short Kt[64][72];     // [key][d]
  __shared__ unsigned short Vt[64][72];     // [d][key]
  __shared__ float Obuf[64][68];            // [query][d] fp32 merge buffer
  __shared__ float Lm[4][64], Ll[4][64], Sc[4][64], Linv[64];
  int tid = threadIdx.x, w = tid >> 6, l = tid & 63;
  int quad = l >> 4, m16 = l & 15;
  const size_t base = (size_t)bh * HWN * DHD;

  for (int i = tid; i < 64 * 68; i += 256) ((float*)Obuf)[i] = 0.f;

  // Q frags: all 64 queries (4 j-tiles), B-operand position, from global once.
  bf16x8 qf[4][2];
#pragma unroll
  for (int j = 0; j < 4; ++j) {
    int qrow = qt * 64 + j * 16 + m16;
    const unsigned short* qp = q + base + (size_t)qrow * 64 + quad * 8;
    qf[j][0] = *(const bf16x8*)qp;
    qf[j][1] = *(const bf16x8*)(qp + 32);
  }

  // acc[j*4+dt]: O_w[query = j*16+quad*4+i][d = dt*16+m16]
  floatx4 acc[16] = {};
  float m_[4] = {-1e30f, -1e30f, -1e30f, -1e30f};
  float l_[4] = {};

  for (int kt = 0; kt < 64; ++kt) {
    __syncthreads();
#pragma unroll
    for (int pp = 0; pp < 2; ++pp) {
      int f = (pp * 256 + tid) * 8;
      int r = f >> 6, c = f & 63;
      *(uint4*)&Kt[r][c] = *(const uint4*)(k  + base + (size_t)(kt * 64 + r) * 64 + c);
      *(uint4*)&Vt[r][c] = *(const uint4*)(vt + base + (size_t)r * 4096 + kt * 64 + c);
    }
    __syncthreads();
    // S slice: A = K rows {w*16+m16}, B = qf[j]. Lane holds
    // S[key = w*16+quad*4+i][query = j*16+m16] (log2 domain).
    bf16x8 kf0 = *(const bf16x8*)&Kt[w * 16 + m16][quad * 8];
    bf16x8 kf1 = *(const bf16x8*)&Kt[w * 16 + m16][32 + quad * 8];
    floatx4 s[4];
#pragma unroll
    for (int j = 0; j < 4; ++j) {
      floatx4 z = {};
      z = __builtin_amdgcn_mfma_f32_16x16x32_bf16(kf0, qf[j][0], z, 0, 0, 0);
      s[j] = __builtin_amdgcn_mfma_f32_16x16x32_bf16(kf1, qf[j][1], z, 0, 0, 0);
    }
    // online softmax per query (j, m16): in-lane over i + quad reduction
    float mx[4], mn[4], rs[4];
    bool grew = false;
#pragma unroll
    for (int j = 0; j < 4; ++j) {
      mx[j] = fmaxf(fmaxf(s[j][0], s[j][1]), fmaxf(s[j][2], s[j][3]));
      mx[j] = fmaxf(mx[j], __shfl_xor(mx[j], 16));
      mx[j] = fmaxf(mx[j], __shfl_xor(mx[j], 32));
      grew |= (mx[j] > m_[j]);
      mn[j] = fmaxf(m_[j], mx[j]);
    }
#pragma unroll
    for (int j = 0; j < 4; ++j) {
      rs[j] = 0.f;
#pragma unroll
      for (int i = 0; i < 4; ++i) {
        float p = fast_exp2(s[j][i] - mn[j]);
        s[j][i] = p;
        rs[j] += p;
      }
      rs[j] += __shfl_xor(rs[j], 16);
      rs[j] += __shfl_xor(rs[j], 32);
    }
    if (__ballot(grew)) {
#pragma unroll
      for (int j = 0; j < 4; ++j) {
        float a = fast_exp2(m_[j] - mn[j]);
        l_[j] = l_[j] * a + rs[j];
#pragma unroll
        for (int i = 0; i < 4; ++i) {
          // alpha of query j*16+quad*4+i lives in lane m16 = quad*4+i
          float ab = __shfl(a, (l & 48) + quad * 4 + i);
#pragma unroll
          for (int dt = 0; dt < 4; ++dt) acc[j * 4 + dt][i] *= ab;
        }
      }
    } else {
#pragma unroll
      for (int j = 0; j < 4; ++j) l_[j] += rs[j];
    }
#pragma unroll
    for (int j = 0; j < 4; ++j) m_[j] = mn[j];
    // P -> bf16 A-frags via v_perm; P is already in A-position for PV
    bf16x4 pf[4];
#pragma unroll
    for (int j = 0; j < 4; ++j) {
      union { unsigned u[2]; bf16x4 v; } pu;
      pu.u[0] = pack_bf16_trunc(s[j][0], s[j][1]);
      pu.u[1] = pack_bf16_trunc(s[j][2], s[j][3]);
      pf[j] = pu.v;
    }
    // O_w += P * V_slice : B-frag = Vt[dt*16+m16][w*16+quad*4], 4 b64 reads
#pragma unroll
    for (int dt = 0; dt < 4; ++dt) {
      bf16x4 vf = *(const bf16x4*)&Vt[dt * 16 + m16][w * 16 + quad * 4];
#pragma unroll
      for (int j = 0; j < 4; ++j)
        acc[j * 4 + dt] = __builtin_amdgcn_mfma_f32_16x16x16bf16_1k(pf[j], vf, acc[j * 4 + dt], 0, 0, 0);
    }
  }

  // ---- merge 4 per-wave partials (log-sum-exp combine) ----
  // lane l = quad*16+m16 writes stats of query l (j = quad): avoid dynamic
  // register-array indexing (scratch!) via cndmask chain.
  float mw = (quad == 0) ? m_[0] : (quad == 1) ? m_[1] : (quad == 2) ? m_[2] : m_[3];
  float lw = (quad == 0) ? l_[0] : (quad == 1) ? l_[1] : (quad == 2) ? l_[2] : l_[3];
  Lm[w][l] = mw;
  Ll[w][l] = lw;
  __syncthreads();
  if (w == 0) {
    float m0 = Lm[0][l], m1 = Lm[1][l], m2 = Lm[2][l], m3 = Lm[3][l];
    float ms = fmaxf(fmaxf(m0, m1), fmaxf(m2, m3));
    float s0 = fast_exp2(m0 - ms), s1 = fast_exp2(m1 - ms);
    float s2 = fast_exp2(m2 - ms), s3 = fast_exp2(m3 - ms);
    float denom = s0 * Ll[0][l] + s1 * Ll[1][l] + s2 * Ll[2][l] + s3 * Ll[3][l];
    Sc[0][l] = s0; Sc[1][l] = s1; Sc[2][l] = s2; Sc[3][l] = s3;
    Linv[l] = 1.f / denom;
  }
  __syncthreads();
#pragma unroll
  for (int j = 0; j < 4; ++j)
#pragma unroll
    for (int i = 0; i < 4; ++i) {
      float sc = Sc[w][j * 16 + quad * 4 + i];
#pragma unroll
      for (int dt = 0; dt < 4; ++dt)
        atomicAdd(&Obuf[j * 16 + quad * 4 + i][dt * 16 + m16], acc[j * 4 + dt][i] * sc);
    }
  __syncthreads();
  // readback: thread -> (query, 16-d segment); coalesced 32B stores
  {
    int qq = tid >> 2, dseg = (tid & 3) * 16;
    float inv = Linv[qq];
    unsigned short u[16];
#pragma unroll
    for (int z = 0; z < 16; ++z) u[z] = f2b(Obuf[qq][dseg + z] * inv);
    unsigned short* op = o + ((size_t)(b * 4096 + qt * 64 + qq)) * 512 + h * 64 + dseg;
    *(uint4*)op       = *(uint4*)u;
    *(uint4*)(op + 8) = *(uint4*)(u + 8);
  }
}

// ---------------- 6. out-proj + bias + residual, coalesced fp32 store ----------------
__global__ __launch_bounds__(256) void gemm_out(
    const unsigned short* __restrict__ o, const unsigned short* __restrict__ Wp,
    const float* __restrict__ bp, const float* __restrict__ x,
    float* __restrict__ out) {
  int C0 = blockIdx.x * 64, P0 = blockIdx.y * 64, b = blockIdx.z;
  __shared__ unsigned short At[64][72];   // Wp rows (channel)
  __shared__ unsigned short Bt[64][72];   // o rows (pixel)
  int tid = threadIdx.x, w = tid >> 6, l = tid & 63;
  int quad = l >> 4, m16 = l & 15;
  floatx4 acc[4] = {};
  for (int k0 = 0; k0 < 512; k0 += 64) {
    __syncthreads();
#pragma unroll
    for (int pp = 0; pp < 2; ++pp) {
      int f = (pp * 256 + tid) * 8;
      int r = f >> 6, c = f & 63;
      *(uint4*)&At[r][c] = *(const uint4*)(Wp + (size_t)(C0 + r) * 512 + k0 + c);
      *(uint4*)&Bt[r][c] = *(const uint4*)(o + ((size_t)(b * 4096 + P0 + r)) * 512 + k0 + c);
    }
    __syncthreads();
    bf16x8 af0 = *(const bf16x8*)&At[w * 16 + m16][quad * 8];
    bf16x8 af1 = *(const bf16x8*)&At[w * 16 + m16][32 + quad * 8];
#pragma unroll
    for (int nt = 0; nt < 4; ++nt) {
      bf16x8 b0 = *(const bf16x8*)&Bt[nt * 16 + m16][quad * 8];
      bf16x8 b1 = *(const bf16x8*)&Bt[nt * 16 + m16][32 + quad * 8];
      acc[nt] = __builtin_amdgcn_mfma_f32_16x16x32_bf16(af0, b0, acc[nt], 0, 0, 0);
      acc[nt] = __builtin_amdgcn_mfma_f32_16x16x32_bf16(af1, b1, acc[nt], 0, 0, 0);
    }
  }
#pragma unroll
  for (int r = 0; r < 4; ++r) {
    int c = C0 + w * 16 + quad * 4 + r;
    float bias = bp[c];
#pragma unroll
    for (int nt = 0; nt < 4; ++nt) {
      int p = P0 + nt * 16 + m16;
      size_t idx = ((size_t)(b * 512 + c)) * 4096 + p;
      out[idx] = acc[nt][r] + bias + x[idx];
    }
  }
}

extern "C" void kernel_launch(void* const* d_in, const int* in_sizes, int n_in,
                              void* d_out, int out_size, void* d_ws, size_t ws_size,
                              hipStream_t stream) {
  const float* x   = (const float*)d_in[0];
  const float* gnw = (const float*)d_in[1];
  const float* gnb = (const float*)d_in[2];
  const float* wq  = (const float*)d_in[3];
  const float* bq  = (const float*)d_in[4];
  const float* wk  = (const float*)d_in[5];
  const float* bk  = (const float*)d_in[6];
  const float* wv  = (const float*)d_in[7];
  const float* bv  = (const float*)d_in[8];
  const float* wp  = (const float*)d_in[9];
  const float* bp  = (const float*)d_in[10];
  float* out = (float*)d_out;

  char* ws = (char*)d_ws;
  float* stat          = (float*)ws;          ws += 1024;
  float* bqkv          = (float*)ws;          ws += 8192;
  unsigned short* Wqkv = (unsigned short*)ws; ws += (size_t)1536 * 512 * 2;
  unsigned short* Wp   = (unsigned short*)ws; ws += (size_t)512 * 512 * 2;
  unsigned short* t    = (unsigned short*)ws; ws += (size_t)8192 * 512 * 2;
  unsigned short* qb   = (unsigned short*)ws; ws += (size_t)8192 * 512 * 2;
  unsigned short* kb   = (unsigned short*)ws; ws += (size_t)8192 * 512 * 2;
  unsigned short* vb   = (unsigned short*)ws; ws += (size_t)8192 * 512 * 2;  // [16][64][4096]
  unsigned short* ob   = (unsigned short*)ws; ws += (size_t)8192 * 512 * 2;

  hipMemsetAsync(stat, 0, 512, stream);
  dim3 g0(64, 8);
  gn_stats<<<g0, 256, 0, stream>>>(x, stat);
  prep_w<<<4103, 256, 0, stream>>>(wq, wk, wv, wp, bq, bk, bv, Wqkv, Wp, bqkv);
  gn_apply<<<1024, 256, 0, stream>>>(x, stat, gnw, gnb, t);
  dim3 g1(128, 24);
  gemm_qkv<<<g1, 256, 0, stream>>>(t, Wqkv, bqkv, qb, kb, vb);
  dim3 g2(64, 16);
  attn<<<g2, 256, 0, stream>>>(qb, kb, vb, ob);
  dim3 g3(8, 64, 2);
  gemm_out<<<g3, 256, 0, stream>>>(ob, Wp, bp, x, out);
}

// Round 7
// 273.041 us; speedup vs baseline: 1.5172x; 1.5172x over previous
//
#include <hip/hip_runtime.h>

// ---- problem constants ----
#define HWN 4096
#define CCH 512
#define NHEAD 8
#define DHD 64
#define NBATCH 2
#define QK_SCALE 0.35355339059327373f   // 64^-0.25
#define LOG2E    1.4426950408889634f

using floatx4 = __attribute__((ext_vector_type(4))) float;
using bf16x8  = __attribute__((ext_vector_type(8))) short;
using bf16x4  = __attribute__((ext_vector_type(4))) short;

__device__ __forceinline__ unsigned short f2b(float f) {
  union { float f; unsigned u; } x; x.f = f;
  unsigned r = x.u + 0x7FFFu + ((x.u >> 16) & 1u);
  return (unsigned short)(r >> 16);
}

__device__ __forceinline__ float fast_exp2(float x) {
#if __has_builtin(__builtin_amdgcn_exp2f)
  return __builtin_amdgcn_exp2f(x);
#else
  return __expf(x * 0.69314718056f);
#endif
}

// pack bf16(lo),bf16(hi) from two floats in ONE v_perm_b32 (truncating round)
__device__ __forceinline__ unsigned pack_bf16_trunc(float lo, float hi) {
  return __builtin_amdgcn_perm(__float_as_uint(hi), __float_as_uint(lo), 0x07060302u);
}

// ---------------- 1. GroupNorm partial sums: grid (64 groups, 8 parts) ----------------
__global__ __launch_bounds__(256) void gn_stats(const float* __restrict__ x,
                                                float* __restrict__ stat) {
  int bg = blockIdx.x;
  const float4* p = (const float4*)(x + (size_t)bg * 65536) + blockIdx.y * 2048;
  float s = 0.f, ss = 0.f;
  for (int i = threadIdx.x; i < 2048; i += 256) {
    float4 v = p[i];
    s  += v.x + v.y + v.z + v.w;
    ss += v.x*v.x + v.y*v.y + v.z*v.z + v.w*v.w;
  }
  for (int off = 32; off; off >>= 1) {
    s  += __shfl_xor(s, off);
    ss += __shfl_xor(ss, off);
  }
  __shared__ float red[8];
  int w = threadIdx.x >> 6;
  if ((threadIdx.x & 63) == 0) { red[w] = s; red[4 + w] = ss; }
  __syncthreads();
  if (threadIdx.x == 0) {
    float S  = red[0] + red[1] + red[2] + red[3];
    float SS = red[4] + red[5] + red[6] + red[7];
    atomicAdd(&stat[bg], S);
    atomicAdd(&stat[64 + bg], SS);
  }
}

// ---------------- 2. weight prep: fp32 -> bf16, fold SCALE (and log2e into q) ----------------
__global__ __launch_bounds__(256) void prep_w(
    const float* __restrict__ wq, const float* __restrict__ wk,
    const float* __restrict__ wv, const float* __restrict__ wp,
    const float* __restrict__ bq, const float* __restrict__ bk,
    const float* __restrict__ bv,
    unsigned short* __restrict__ Wqkv, unsigned short* __restrict__ Wp,
    float* __restrict__ bqkv) {
  int i = blockIdx.x * 256 + threadIdx.x;
  if (i < 786432) {                       // Wqkv: rows 0-511 q, 512-1023 k, 1024-1535 v
    int row = i >> 9;
    float v;
    if (row < 512)       v = wq[i] * (QK_SCALE * LOG2E);
    else if (row < 1024) v = wk[i - 262144] * QK_SCALE;
    else                 v = wv[i - 524288];
    Wqkv[i] = f2b(v);
  } else if (i < 1048576) {
    Wp[i - 786432] = f2b(wp[i - 786432]);
  } else if (i < 1050112) {
    int j = i - 1048576;
    float v = (j < 512) ? bq[j] * (QK_SCALE * LOG2E)
            : (j < 1024) ? bk[j - 512] * QK_SCALE
            : bv[j - 1024];
    bqkv[j] = v;
  }
}

// ---------------- 3. normalize + transpose to t[(b*4096+p)*512 + c] bf16 ----------------
__global__ __launch_bounds__(256) void gn_apply(
    const float* __restrict__ x, const float* __restrict__ stat,
    const float* __restrict__ gnw, const float* __restrict__ gnb,
    unsigned short* __restrict__ t) {
  int pt = blockIdx.x & 63;
  int ct = (blockIdx.x >> 6) & 7;
  int b  = blockIdx.x >> 9;
  int c0 = ct * 64, p0 = pt * 64;
  __shared__ float tile[64][68];          // pad 68: bank shift 4/row, float4-aligned
  int tid = threadIdx.x;
  for (int pp = 0; pp < 4; ++pp) {
    int f = (pp * 256 + tid) * 4;
    int cl = f >> 6, pl = f & 63;
    int c = c0 + cl;
    float4 v = *(const float4*)(x + ((size_t)(b * 512 + c)) * 4096 + p0 + pl);
    int g = c >> 4;
    float S    = stat[b * 32 + g];
    float SS   = stat[64 + b * 32 + g];
    float mean = S * (1.f / 65536.f);
    float var  = SS * (1.f / 65536.f) - mean * mean;
    float rstd = rsqrtf(var + 1e-5f);
    float w  = gnw[c] * rstd;
    float bb = gnb[c] - mean * w;
    tile[cl][pl + 0] = v.x * w + bb;
    tile[cl][pl + 1] = v.y * w + bb;
    tile[cl][pl + 2] = v.z * w + bb;
    tile[cl][pl + 3] = v.w * w + bb;
  }
  __syncthreads();
  for (int pp = 0; pp < 2; ++pp) {
    int f = (pp * 256 + tid) * 8;
    int pl = f >> 6, cl = f & 63;
    unsigned short u[8];
#pragma unroll
    for (int j = 0; j < 8; ++j) u[j] = f2b(tile[cl + j][pl]);
    *(uint4*)(t + ((size_t)(b * 4096 + p0 + pl)) * 512 + c0 + cl) = *(uint4*)u;
  }
}

// ---------------- 4. QKV GEMM ----------------
// q/k: [(bh*4096+p)*64+d] bf16 ; v: TRANSPOSED [bh][d][4096] bf16
__global__ __launch_bounds__(256) void gemm_qkv(
    const unsigned short* __restrict__ t, const unsigned short* __restrict__ Wqkv,
    const float* __restrict__ bqkv,
    unsigned short* __restrict__ qo, unsigned short* __restrict__ ko,
    unsigned short* __restrict__ vo) {
  int M0 = blockIdx.x * 64;   // pixel 0..8128
  int N0 = blockIdx.y * 64;   // outch 0..1472
  __shared__ unsigned short At[64][72];
  __shared__ unsigned short Bt[64][72];
  int tid = threadIdx.x, w = tid >> 6, l = tid & 63;
  int quad = l >> 4, m16 = l & 15;
  floatx4 acc[4] = {};
  for (int k0 = 0; k0 < 512; k0 += 64) {
    __syncthreads();
#pragma unroll
    for (int pp = 0; pp < 2; ++pp) {
      int f = (pp * 256 + tid) * 8;
      int r = f >> 6, c = f & 63;
      *(uint4*)&At[r][c] = *(const uint4*)(t    + (size_t)(M0 + r) * 512 + k0 + c);
      *(uint4*)&Bt[r][c] = *(const uint4*)(Wqkv + (size_t)(N0 + r) * 512 + k0 + c);
    }
    __syncthreads();
    bf16x8 af0 = *(const bf16x8*)&At[w * 16 + m16][quad * 8];
    bf16x8 af1 = *(const bf16x8*)&At[w * 16 + m16][32 + quad * 8];
#pragma unroll
    for (int nt = 0; nt < 4; ++nt) {
      bf16x8 b0 = *(const bf16x8*)&Bt[nt * 16 + m16][quad * 8];
      bf16x8 b1 = *(const bf16x8*)&Bt[nt * 16 + m16][32 + quad * 8];
      acc[nt] = __builtin_amdgcn_mfma_f32_16x16x32_bf16(af0, b0, acc[nt], 0, 0, 0);
      acc[nt] = __builtin_amdgcn_mfma_f32_16x16x32_bf16(af1, b1, acc[nt], 0, 0, 0);
    }
  }
  int which = N0 >> 9;
  int head  = (N0 & 511) >> 6;
  if (which == 2) {
    // V: transpose 64x64 tile through LDS, store [bh][d][4096] coalesced
    __syncthreads();
#pragma unroll
    for (int nt = 0; nt < 4; ++nt) {
      int d = nt * 16 + m16;
      float bias = bqkv[N0 + d];
#pragma unroll
      for (int r = 0; r < 4; ++r)
        At[d][w * 16 + quad * 4 + r] = f2b(acc[nt][r] + bias);
    }
    __syncthreads();
    int bb = M0 >> 12, p0 = M0 & 4095;
    unsigned short* dst = vo + ((size_t)(bb * 8 + head) * 64) * 4096;
#pragma unroll
    for (int pp = 0; pp < 2; ++pp) {
      int f = (pp * 256 + tid) * 8;
      int d = f >> 6, pl = f & 63;
      *(uint4*)(dst + (size_t)d * 4096 + p0 + pl) = *(uint4*)&At[d][pl];
    }
  } else {
    unsigned short* dst = (which == 0) ? qo : ko;
#pragma unroll
    for (int nt = 0; nt < 4; ++nt) {
      int n = N0 + nt * 16 + m16;
      float bias = bqkv[n];
      int d = n & 63;
#pragma unroll
      for (int r = 0; r < 4; ++r) {
        int m = M0 + w * 16 + quad * 4 + r;   // pixel 0..8191
        int b = m >> 12, p = m & 4095;
        dst[(((size_t)(b * 8 + head) * 4096 + p) << 6) + d] = f2b(acc[nt][r] + bias);
      }
    }
  }
}

// ---------------- 5. flash attention per (bh, 64-query tile) ----------------
// R5 structure (query-slice waves, S^T=K*Q^T, log2 scores, v_perm pack,
// skip-rescale) with K-TILE=128: halves barrier rounds and amortizes the
// per-round softmax reductions / rescale / broadcasts over 2x keys.
// (256,4): VGPR cap 128 (s[8] needs 32 regs; R5-proven code shape, no
// cross-barrier prefetch arrays -> no scratch spill; tripwire = WRITE_SIZE).
__global__ __launch_bounds__(256, 4) void attn(
    const unsigned short* __restrict__ q, const unsigned short* __restrict__ k,
    const unsigned short* __restrict__ vt, unsigned short* __restrict__ o) {
  int qt = blockIdx.x;           // 0..63
  int bh = blockIdx.y;           // 0..15
  int b = bh >> 3, h = bh & 7;
  __shared__ unsigned short Kt[128][72];    // [key][d]   18.4 KB
  __shared__ unsigned short Vt[64][136];    // [d][key]   17.4 KB
  int tid = threadIdx.x, w = tid >> 6, l = tid & 63;
  int quad = l >> 4, m16 = l & 15;
  const size_t base = (size_t)bh * HWN * DHD;

  bf16x8 qf0, qf1;   // Q[qrow][quad*8+j] -> B-frag of K=32 mfma
  {
    int qrow = qt * 64 + w * 16 + m16;
    const unsigned short* qp = q + base + (size_t)qrow * 64 + quad * 8;
    qf0 = *(const bf16x8*)qp;
    qf1 = *(const bf16x8*)(qp + 32);
  }
  floatx4 accO[4] = {};   // O[q-in-lane][d=dt*16+m16]
  float mrow = -1e30f, lrow = 0.f;   // per-lane scalars, query = m16

  for (int kt = 0; kt < 32; ++kt) {
    __syncthreads();
#pragma unroll
    for (int pp = 0; pp < 4; ++pp) {
      int f = (pp * 256 + tid) * 8;
      int rk = f >> 6, ck = f & 63;       // K: 128 rows x 64
      *(uint4*)&Kt[rk][ck] = *(const uint4*)(k + base + (size_t)(kt * 128 + rk) * 64 + ck);
      int rv = f >> 7, cv = f & 127;      // V: 64 rows x 128
      *(uint4*)&Vt[rv][cv] = *(const uint4*)(vt + base + (size_t)rv * 4096 + kt * 128 + cv);
    }
    __syncthreads();
    // S^T = K * Q^T : lane holds S[q=m16][key = nt*16 + quad*4 + i] (log2 dom.)
    floatx4 s[8];
#pragma unroll
    for (int nt = 0; nt < 8; ++nt) {
      bf16x8 kf0 = *(const bf16x8*)&Kt[nt * 16 + m16][quad * 8];
      bf16x8 kf1 = *(const bf16x8*)&Kt[nt * 16 + m16][32 + quad * 8];
      floatx4 z = {};
      z = __builtin_amdgcn_mfma_f32_16x16x32_bf16(kf0, qf0, z, 0, 0, 0);
      s[nt] = __builtin_amdgcn_mfma_f32_16x16x32_bf16(kf1, qf1, z, 0, 0, 0);
    }
    // online softmax: reduce across quads only (xor 16, 32)
    float mx = s[0][0];
#pragma unroll
    for (int nt = 0; nt < 8; ++nt)
#pragma unroll
      for (int i = 0; i < 4; ++i) mx = fmaxf(mx, s[nt][i]);
    mx = fmaxf(mx, __shfl_xor(mx, 16));
    mx = fmaxf(mx, __shfl_xor(mx, 32));
    bool grew = mx > mrow;
    float mnew = fmaxf(mrow, mx);
    float rs = 0.f;
#pragma unroll
    for (int nt = 0; nt < 8; ++nt)
#pragma unroll
      for (int i = 0; i < 4; ++i) {
        float p = fast_exp2(s[nt][i] - mnew);
        s[nt][i] = p;
        rs += p;
      }
    rs += __shfl_xor(rs, 16);
    rs += __shfl_xor(rs, 32);
    if (__ballot(grew)) {
      float alpha = fast_exp2(mrow - mnew);
      float al0 = __shfl(alpha, quad * 4 + 0);
      float al1 = __shfl(alpha, quad * 4 + 1);
      float al2 = __shfl(alpha, quad * 4 + 2);
      float al3 = __shfl(alpha, quad * 4 + 3);
#pragma unroll
      for (int dt = 0; dt < 4; ++dt) {
        accO[dt][0] *= al0; accO[dt][1] *= al1;
        accO[dt][2] *= al2; accO[dt][3] *= al3;
      }
      lrow = lrow * alpha + rs;
    } else {
      lrow += rs;
    }
    mrow = mnew;
    // P -> bf16 A-frags via v_perm (1 inst / 2 values)
    bf16x4 pf[8];
#pragma unroll
    for (int nt = 0; nt < 8; ++nt) {
      union { unsigned u[2]; bf16x4 v; } pu;
      pu.u[0] = pack_bf16_trunc(s[nt][0], s[nt][1]);
      pu.u[1] = pack_bf16_trunc(s[nt][2], s[nt][3]);
      pf[nt] = pu.v;
    }
    // O += P*V : B-frag = Vt[d=dt*16+m16][key = nt*16+quad*4], contiguous b64
#pragma unroll
    for (int dt = 0; dt < 4; ++dt) {
#pragma unroll
      for (int nt = 0; nt < 8; ++nt) {
        bf16x4 vf = *(const bf16x4*)&Vt[dt * 16 + m16][nt * 16 + quad * 4];
        accO[dt] = __builtin_amdgcn_mfma_f32_16x16x16bf16_1k(pf[nt], vf, accO[dt], 0, 0, 0);
      }
    }
  }
  // epilogue: o[(b*4096+q)*512 + h*64 + d], divide by l of query quad*4+i
  float li0 = 1.f / __shfl(lrow, quad * 4 + 0);
  float li1 = 1.f / __shfl(lrow, quad * 4 + 1);
  float li2 = 1.f / __shfl(lrow, quad * 4 + 2);
  float li3 = 1.f / __shfl(lrow, quad * 4 + 3);
#pragma unroll
  for (int dt = 0; dt < 4; ++dt) {
    int d = dt * 16 + m16;
    int qrow = qt * 64 + w * 16 + quad * 4;
    size_t rowb = ((size_t)(b * 4096 + qrow)) * 512 + h * 64 + d;
    o[rowb]           = f2b(accO[dt][0] * li0);
    o[rowb + 512]     = f2b(accO[dt][1] * li1);
    o[rowb + 1024]    = f2b(accO[dt][2] * li2);
    o[rowb + 1536]    = f2b(accO[dt][3] * li3);
  }
}

// ---------------- 6. out-proj + bias + residual, coalesced fp32 store ----------------
__global__ __launch_bounds__(256) void gemm_out(
    const unsigned short* __restrict__ o, const unsigned short* __restrict__ Wp,
    const float* __restrict__ bp, const float* __restrict__ x,
    float* __restrict__ out) {
  int C0 = blockIdx.x * 64, P0 = blockIdx.y * 64, b = blockIdx.z;
  __shared__ unsigned short At[64][72];   // Wp rows (channel)
  __shared__ unsigned short Bt[64][72];   // o rows (pixel)
  int tid = threadIdx.x, w = tid >> 6, l = tid & 63;
  int quad = l >> 4, m16 = l & 15;
  floatx4 acc[4] = {};
  for (int k0 = 0; k0 < 512; k0 += 64) {
    __syncthreads();
#pragma unroll
    for (int pp = 0; pp < 2; ++pp) {
      int f = (pp * 256 + tid) * 8;
      int r = f >> 6, c = f & 63;
      *(uint4*)&At[r][c] = *(const uint4*)(Wp + (size_t)(C0 + r) * 512 + k0 + c);
      *(uint4*)&Bt[r][c] = *(const uint4*)(o + ((size_t)(b * 4096 + P0 + r)) * 512 + k0 + c);
    }
    __syncthreads();
    bf16x8 af0 = *(const bf16x8*)&At[w * 16 + m16][quad * 8];
    bf16x8 af1 = *(const bf16x8*)&At[w * 16 + m16][32 + quad * 8];
#pragma unroll
    for (int nt = 0; nt < 4; ++nt) {
      bf16x8 b0 = *(const bf16x8*)&Bt[nt * 16 + m16][quad * 8];
      bf16x8 b1 = *(const bf16x8*)&Bt[nt * 16 + m16][32 + quad * 8];
      acc[nt] = __builtin_amdgcn_mfma_f32_16x16x32_bf16(af0, b0, acc[nt], 0, 0, 0);
      acc[nt] = __builtin_amdgcn_mfma_f32_16x16x32_bf16(af1, b1, acc[nt], 0, 0, 0);
    }
  }
#pragma unroll
  for (int r = 0; r < 4; ++r) {
    int c = C0 + w * 16 + quad * 4 + r;
    float bias = bp[c];
#pragma unroll
    for (int nt = 0; nt < 4; ++nt) {
      int p = P0 + nt * 16 + m16;
      size_t idx = ((size_t)(b * 512 + c)) * 4096 + p;
      out[idx] = acc[nt][r] + bias + x[idx];
    }
  }
}

extern "C" void kernel_launch(void* const* d_in, const int* in_sizes, int n_in,
                              void* d_out, int out_size, void* d_ws, size_t ws_size,
                              hipStream_t stream) {
  const float* x   = (const float*)d_in[0];
  const float* gnw = (const float*)d_in[1];
  const float* gnb = (const float*)d_in[2];
  const float* wq  = (const float*)d_in[3];
  const float* bq  = (const float*)d_in[4];
  const float* wk  = (const float*)d_in[5];
  const float* bk  = (const float*)d_in[6];
  const float* wv  = (const float*)d_in[7];
  const float* bv  = (const float*)d_in[8];
  const float* wp  = (const float*)d_in[9];
  const float* bp  = (const float*)d_in[10];
  float* out = (float*)d_out;

  char* ws = (char*)d_ws;
  float* stat          = (float*)ws;          ws += 1024;
  float* bqkv          = (float*)ws;          ws += 8192;
  unsigned short* Wqkv = (unsigned short*)ws; ws += (size_t)1536 * 512 * 2;
  unsigned short* Wp   = (unsigned short*)ws; ws += (size_t)512 * 512 * 2;
  unsigned short* t    = (unsigned short*)ws; ws += (size_t)8192 * 512 * 2;
  unsigned short* qb   = (unsigned short*)ws; ws += (size_t)8192 * 512 * 2;
  unsigned short* kb   = (unsigned short*)ws; ws += (size_t)8192 * 512 * 2;
  unsigned short* vb   = (unsigned short*)ws; ws += (size_t)8192 * 512 * 2;  // [16][64][4096]
  unsigned short* ob   = (unsigned short*)ws; ws += (size_t)8192 * 512 * 2;

  hipMemsetAsync(stat, 0, 512, stream);
  dim3 g0(64, 8);
  gn_stats<<<g0, 256, 0, stream>>>(x, stat);
  prep_w<<<4103, 256, 0, stream>>>(wq, wk, wv, wp, bq, bk, bv, Wqkv, Wp, bqkv);
  gn_apply<<<1024, 256, 0, stream>>>(x, stat, gnw, gnb, t);
  dim3 g1(128, 24);
  gemm_qkv<<<g1, 256, 0, stream>>>(t, Wqkv, bqkv, qb, kb, vb);
  dim3 g2(64, 16);
  attn<<<g2, 256, 0, stream>>>(qb, kb, vb, ob);
  dim3 g3(8, 64, 2);
  gemm_out<<<g3, 256, 0, stream>>>(ob, Wp, bp, x, out);
}